// Round 11
// baseline (167.482 us; speedup 1.0000x reference)
//
#include <hip/hip_runtime.h>
#include <math.h>

// Problem constants (from reference setup_inputs)
#define L0      3072
#define BATCH   1024
#define NNEG    512
#define LDP     264   // padded bf16 row stride in LDS (breaks 512B bank wrap)

typedef __attribute__((ext_vector_type(8))) short bf16x8;
typedef __attribute__((ext_vector_type(4))) float f32x4;

// -------- workspace layout (float offsets) --------
// X0/Y0 : bf16 @ 0        (2 x 393216 bf16 = 393216 floats total)
// H     : float @ 393216  (3072*512 = 1572864)         -> ends 1966080
// R     : float @ 1966080 (3072*256 = 786432)          -> ends 2752512
// Rb    : bf16  @ 2752512 (3072*256 bf16 = 393216 fl)  -> ends 3145728
// spPos @ 3145728, spNeg @ 3145729, rank @ 3145730 (1024 ints),
// counter @ 3145730+1024  (zero block: 1027 words from spPos)

__device__ __forceinline__ float bf2f(unsigned short u) {
  return __uint_as_float(((unsigned)u) << 16);
}
__device__ __forceinline__ void store_out(float v, float* p) { *p = v; }
__device__ __forceinline__ void store_out(float v, unsigned short* p) {
  unsigned x = __float_as_uint(v);                 // f32 -> bf16 RNE
  *p = (unsigned short)((x + 0x7fff + ((x >> 16) & 1)) >> 16);
}

// Half-split matmul, 6 rows x 256 cols per 512-thread block (grid 512).
// A-tile in LDS (broadcast ds_read_b128); W coalesced from global.
// NORM: fused row L2-normalization. OutB: optional second bf16 output (Rb).
template<int K, int AW, int HOFF, bool NORM, typename OutT>
__global__ __launch_bounds__(512) void k_mm(
    const float* __restrict__ Ain,
    const float* __restrict__ W0, const float* __restrict__ W1,
    OutT* __restrict__ Out, const int ldo, const int outHalfOff,
    unsigned short* __restrict__ OutB,
    float* __restrict__ zbuf, const int zcount) {
  __shared__ float AT[6 * AW];
  __shared__ float rs[8][3];
  const int t = threadIdx.x;
  if (zbuf != nullptr && blockIdx.x == 0)
    for (int z = t; z < zcount; z += 512) zbuf[z] = 0.f;
  const int base = blockIdx.x * 6;
  {
    const float4* __restrict__ src = (const float4*)(Ain + base * AW);
    float4* __restrict__ dst = (float4*)AT;
    for (int idx = t; idx < 6 * AW / 4; idx += 512) dst[idx] = src[idx];
  }
  __syncthreads();

  const int wave = t >> 6;
  const int half = wave >> 2;
  const int colg = (wave >> 1) & 1;
  const int rowg = wave & 1;
  const int rg = rowg * 3;
  const int col = colg * 64 + (t & 63);
  const float* __restrict__ W = (half ? W1 : W0) + col;
  const float* __restrict__ A0 = AT + rg * AW + half * HOFF;

  float acc[3] = {0.f, 0.f, 0.f};
#pragma unroll 4
  for (int d = 0; d < K; d += 4) {
    float4 a[3];
#pragma unroll
    for (int r = 0; r < 3; ++r) a[r] = *(const float4*)&A0[r * AW + d];
    float w[4];
#pragma unroll
    for (int i2 = 0; i2 < 4; ++i2) w[i2] = W[(d + i2) * 128];
#pragma unroll
    for (int i2 = 0; i2 < 4; ++i2)
#pragma unroll
      for (int r = 0; r < 3; ++r)
        acc[r] = fmaf(((const float*)&a[r])[i2], w[i2], acc[r]);
  }

  float scale[3] = {1.f, 1.f, 1.f};
  if (NORM) {
    float p[3];
#pragma unroll
    for (int r = 0; r < 3; ++r) p[r] = acc[r] * acc[r];
#pragma unroll
    for (int off = 32; off > 0; off >>= 1)
#pragma unroll
      for (int r = 0; r < 3; ++r) p[r] += __shfl_xor(p[r], off, 64);
    if ((t & 63) == 0) { rs[wave][0] = p[0]; rs[wave][1] = p[1]; rs[wave][2] = p[2]; }
    __syncthreads();
#pragma unroll
    for (int r = 0; r < 3; ++r) {
      const float s = rs[rowg][r] + rs[rowg + 2][r] + rs[rowg + 4][r] + rs[rowg + 6][r];
      scale[r] = rsqrtf(fmaxf(s, 1e-12f));
    }
  }
  OutT* __restrict__ O = Out + half * outHalfOff;
#pragma unroll
  for (int r = 0; r < 3; ++r) {
    const float v = acc[r] * scale[r];
    store_out(v, &O[(base + rg + r) * ldo + col]);
    if (OutB != nullptr)
      store_out(v, &OutB[(base + rg + r) * 256 + half * 128 + col]);
  }
}

// Fused layer-0 + layer-1 aggregation, bf16 gathers, ONE barrier.
// (unchanged from R6/R9 — see journal)
__global__ __launch_bounds__(640) void k_aggregate(
    const unsigned short* __restrict__ X0, const unsigned short* __restrict__ Y0,
    const int* __restrict__ nb0, const int* __restrict__ nb1,
    const int* __restrict__ nb2, float* __restrict__ H) {
  __shared__ float gB[10][128], gC[10][128], gD[10][128];
  const int i = blockIdx.x;
  const int t = threadIdx.x;
  const int n0 = nb0[i];
  const int j = t >> 6;
  const int lam = t & 63;
  const int r = i * 10 + j;
  int myidx = 0;
  if (lam < 25) myidx = nb2[r * 25 + lam];
  else if (lam == 25) myidx = nb1[r];
  const int c8 = lam & 15;
  const int sub = lam >> 4;

  float d8[8];
#pragma unroll
  for (int e = 0; e < 8; ++e) d8[e] = 0.f;
#pragma unroll
  for (int m = 0; m < 7; ++m) {
    const int k = sub + 4 * m;
    const int ridx = __shfl(myidx, k, 64);
    if (k < 25) {
      const float4 raw = *(const float4*)(Y0 + ridx * 128 + c8 * 8);
      const unsigned short* u = (const unsigned short*)&raw;
#pragma unroll
      for (int e = 0; e < 8; ++e) d8[e] += bf2f(u[e]);
    }
  }
#pragma unroll
  for (int e = 0; e < 8; ++e) d8[e] += __shfl_xor(d8[e], 16, 64);
#pragma unroll
  for (int e = 0; e < 8; ++e) d8[e] += __shfl_xor(d8[e], 32, 64);

  const int r1 = __shfl(myidx, 25, 64);
  if (sub == 0) {
#pragma unroll
    for (int e = 0; e < 8; ++e) gD[j][c8 * 8 + e] = fmaxf(d8[e] * 0.04f, 0.f);
    const float4 raw = *(const float4*)(Y0 + r1 * 128 + c8 * 8);
    const unsigned short* u = (const unsigned short*)&raw;
#pragma unroll
    for (int e = 0; e < 8; ++e) gB[j][c8 * 8 + e] = bf2f(u[e]);
  } else if (sub == 1) {
    const float4 raw = *(const float4*)(X0 + r1 * 128 + c8 * 8);
    const unsigned short* u = (const unsigned short*)&raw;
#pragma unroll
    for (int e = 0; e < 8; ++e) gC[j][c8 * 8 + e] = fmaxf(bf2f(u[e]), 0.f);
  }
  __syncthreads();

  if (t < 512) {
    const int q = t >> 7, c = t & 127;
    float v;
    if (q == 0) {
      v = fmaxf(bf2f(X0[n0 * 128 + c]), 0.f);
    } else {
      const float* g = (q == 1) ? &gB[0][0] : (q == 2) ? &gC[0][0] : &gD[0][0];
      float s = 0.f;
#pragma unroll
      for (int jj = 0; jj < 10; ++jj) s += g[jj * 128 + c];
      v = s * 0.1f;
      if (q == 1) v = fmaxf(v, 0.f);
    }
    H[i * 512 + t] = v;
  }
}

__device__ __forceinline__ float softplusf(float x) {
  return fmaxf(x, 0.f) + log1pf(expf(-fabsf(x)));
}

// MEGA k_neg: 32 src rows x 64 neg cols per 256-thread block (grid 256,
// LDS 67.6 KB -> 2 blocks/CU). Each block also stages its 32 POS rows and
// recomputes aff via the BIT-IDENTICAL diag-MFMA sequence (same fragments,
// same k0-ascending chain, zero-init) -> tied neg columns reproduce aff
// exactly -> exact-tie rank semantics (positive-last stable argsort).
// colBase==0 blocks own spPos + src_emb copy. The LAST block to finish
// (device-scope counter) computes loss+mrr (rank read via atomicAdd(p,0),
// coherent across XCDs). No separate k_aff / k_finalize dispatches.
__global__ __launch_bounds__(256) void k_neg(
    const unsigned short* __restrict__ Rb, const float* __restrict__ R,
    const int* __restrict__ src_idx, const int* __restrict__ pos_idx,
    const int* __restrict__ neg_idx, float* __restrict__ out,
    int* __restrict__ rank, float* __restrict__ spPos,
    float* __restrict__ spNeg, int* __restrict__ counter) {
  __shared__ unsigned short Sb[32][LDP];
  __shared__ unsigned short Pb[32][LDP];
  __shared__ unsigned short Nb[64][LDP];
  __shared__ float wsum[4];
  __shared__ int lastFlag;
  const int t = threadIdx.x;
  const int rowBase = (blockIdx.x >> 3) * 32;
  const int colBase = (blockIdx.x & 7) * 64;
  const bool first = (colBase == 0);

  // stage 32 src + 32 pos + 64 neg bf16 rows (float4 granularity)
  for (int idx = t; idx < 128 * 32; idx += 256) {
    const int row = idx >> 5, q = idx & 31;
    int gr;
    unsigned short* dst;
    if (row < 32)      { gr = src_idx[rowBase + row];      dst = &Sb[row][0]; }
    else if (row < 64) { gr = pos_idx[rowBase + row - 32]; dst = &Pb[row - 32][0]; }
    else               { gr = neg_idx[colBase + row - 64]; dst = &Nb[row - 64][0]; }
    *(float4*)(dst + q * 8) = ((const float4*)(Rb + gr * 256))[q];
  }
  if (first) {  // src_emb copy to d_out (fp32 R)
    for (int idx = t; idx < 32 * 64; idx += 256) {
      const int rr = idx >> 6, qq = idx & 63;
      ((float4*)out)[(rowBase + rr) * 64 + qq] =
          ((const float4*)R)[src_idx[rowBase + rr] * 64 + qq];
    }
  }
  __syncthreads();

  const int l = t & 63, w = t >> 6;
  const int mt = w & 1, np = w >> 1;
  const int lm = l & 15, quad = l >> 4;
  const unsigned short* Sp = &Sb[mt * 16 + lm][quad * 8];
  const unsigned short* Pp = &Pb[mt * 16 + lm][quad * 8];
  const unsigned short* N0 = &Nb[np * 32 + lm][quad * 8];
  const unsigned short* N1 = &Nb[np * 32 + 16 + lm][quad * 8];
  f32x4 da = {0.f, 0.f, 0.f, 0.f};
  f32x4 d0 = {0.f, 0.f, 0.f, 0.f}, d1 = {0.f, 0.f, 0.f, 0.f};
#pragma unroll
  for (int k0 = 0; k0 < 256; k0 += 32) {
    bf16x8 a  = *(const bf16x8*)(Sp + k0);
    bf16x8 bp = *(const bf16x8*)(Pp + k0);
    bf16x8 b0 = *(const bf16x8*)(N0 + k0);
    bf16x8 b1 = *(const bf16x8*)(N1 + k0);
    da = __builtin_amdgcn_mfma_f32_16x16x32_bf16(a, bp, da, 0, 0, 0);
    d0 = __builtin_amdgcn_mfma_f32_16x16x32_bf16(a, b0, d0, 0, 0, 0);
    d1 = __builtin_amdgcn_mfma_f32_16x16x32_bf16(a, b1, d1, 0, 0, 0);
  }

  // C/D layout: col=lane&15, row=quad*4+j. aff[row] sits in the diag lane
  // (lm == quad*4+j), i.e. lane quad*20+j; broadcast within the wave.
  float sp = 0.f;
#pragma unroll
  for (int j = 0; j < 4; ++j) {
    const int rowq = quad * 4 + j;                 // row within the 16-half
    const float av = __shfl(da[j], quad * 20 + j, 64);
    if (first && np == 0 && lm == rowq)
      atomicAdd(spPos, softplusf(-da[j]));         // diag holder, once per row
    const float v0 = d0[j], v1 = d1[j];
    sp += softplusf(v0) + softplusf(v1);
    int c = (v0 >= av ? 1 : 0) + (v1 >= av ? 1 : 0);
#pragma unroll
    for (int off = 8; off > 0; off >>= 1) c += __shfl_down(c, off, 16);
    if (lm == 0 && c) atomicAdd(&rank[rowBase + mt * 16 + rowq], c);
  }
#pragma unroll
  for (int off = 32; off > 0; off >>= 1) sp += __shfl_down(sp, off, 64);
  if (l == 0) atomicAdd(spNeg, sp);

  // ---- last-block finalize (loss + mrr) ----
  __threadfence();
  __syncthreads();
  if (t == 0) lastFlag = (atomicAdd(counter, 1) == 255) ? 1 : 0;
  __syncthreads();
  if (lastFlag) {
    float s = 0.f;
    for (int i = t; i < BATCH; i += 256) {
      const int rv = atomicAdd(&rank[i], 0);       // coherent read
      s += 1.f / (float)(rv + 1);
    }
#pragma unroll
    for (int off = 32; off > 0; off >>= 1) s += __shfl_down(s, off, 64);
    if ((t & 63) == 0) wsum[t >> 6] = s;
    __syncthreads();
    if (t == 0) {
      const float mrr = (wsum[0] + wsum[1] + wsum[2] + wsum[3]) * (1.f / 1024.f);
      const float pv = atomicAdd(spPos, 0.f);
      const float nv = atomicAdd(spNeg, 0.f);
      out[BATCH * 256]     = (pv + nv) * (1.f / 1024.f);
      out[BATCH * 256 + 1] = mrr;
    }
  }
}

extern "C" void kernel_launch(void* const* d_in, const int* in_sizes, int n_in,
                              void* d_out, int out_size, void* d_ws, size_t ws_size,
                              hipStream_t stream) {
  const float* feat   = (const float*)d_in[1];
  const int* src_idx  = (const int*)d_in[2];
  const int* pos_idx  = (const int*)d_in[3];
  const int* neg_idx  = (const int*)d_in[4];
  const int* nb0      = (const int*)d_in[5];
  const int* nb1      = (const int*)d_in[6];
  const int* nb2      = (const int*)d_in[7];
  const float* ws0    = (const float*)d_in[8];
  const float* wn0    = (const float*)d_in[9];
  const float* ws1    = (const float*)d_in[10];
  const float* wn1    = (const float*)d_in[11];

  float* wsf = (float*)d_ws;
  unsigned short* X0 = (unsigned short*)d_ws;        // bf16[393216]
  unsigned short* Y0 = X0 + 393216;                  // bf16[393216]
  float* H     = wsf + 393216;                       // 3072*512
  float* R     = wsf + 1966080;                      // 3072*256 fp32
  unsigned short* Rb = (unsigned short*)(wsf + 2752512);  // 3072*256 bf16
  float* spPos = wsf + 3145728;                      // AFTER Rb (R10 bug fix)
  float* spNeg = wsf + 3145729;
  int*   rank  = (int*)(wsf + 3145730);              // 1024 ints
  int*   counter = (int*)(wsf + 3145730 + 1024);
  float* out   = (float*)d_out;

  // X0 = bf16(feat@ws0), Y0 = bf16(feat@wn0); block 0 zeroes
  // spPos/spNeg/rank/counter (1027 words)
  k_mm<128, 128, 0, false, unsigned short><<<L0 / 6, 512, 0, stream>>>(
      feat, ws0, wn0, X0, 128, 393216, nullptr, spPos, 1027);
  k_aggregate<<<L0, 640, 0, stream>>>(X0, Y0, nb0, nb1, nb2, H);
  // R = normalized layer-1 output (fp32) + Rb (bf16 copy for MFMA)
  k_mm<256, 512, 256, true, float><<<L0 / 6, 512, 0, stream>>>(
      H, ws1, wn1, R, 256, 128, Rb, nullptr, 0);
  k_neg<<<(BATCH / 32) * (NNEG / 64), 256, 0, stream>>>(
      Rb, R, src_idx, pos_idx, neg_idx, out, rank, spPos, spNeg, counter);
}